// Round 1
// baseline (855.775 us; speedup 1.0000x reference)
//
#include <hip/hip_runtime.h>
#include <hip/hip_bf16.h>

// ---------------------------------------------------------------------------
// MultiHeadSelfAttention (nh=1) restructured through the feature Gram matrix.
//   B=16, S=4096, H=512.  All inputs fp32.
//   G_g   = x_g^T x_g                         (512x512 per batch)
//   SC_g  = (Wq^T G_g Wk)/sqrt(512) + bias rank-1 terms
//   attn  = softmax_rows(SC)
//   Aat_g = attn^T Wo ;  P_g = Wv Aat_g ;  c_g = bv Aat_g + bo
//   out_g = x_g P_g + c_g
// All GEMMs use bf16 hi/lo split (3 MFMA passes) for fp32-class accuracy.
// ---------------------------------------------------------------------------

typedef __attribute__((ext_vector_type(4))) float f32x4;
typedef __attribute__((ext_vector_type(8))) __bf16 bf16x8;
typedef __attribute__((ext_vector_type(4))) __bf16 bf16x4;

typedef __attribute__((address_space(1))) const void gconst_void;
typedef __attribute__((address_space(3))) void lds_void;

__device__ __forceinline__ void gload_lds16(const void* g, void* l) {
  __builtin_amdgcn_global_load_lds((gconst_void*)g, (lds_void*)l, 16, 0, 0);
}

__device__ __forceinline__ void cvt_hilo(float v, __bf16& h, __bf16& l) {
  h = (__bf16)v;
  l = (__bf16)(v - (float)h);
}

// ---------------------------------------------------------------------------
// Generic 128x128-tile GEMM:  C[m][n] = sum_k Ain(m,k)*Bin(n,k)  (+bias[n])*?
//   MODE 0: A,B are fp32 row-major [M][K] / [N][K]; converted to bf16 hi/lo
//           during staging (LDS pitch 72 to spread banks).
//   MODE 1: A,B given as bf16 hi/lo pairs, row-major [.][K]; staged with
//           global_load_lds (linear LDS dest, XOR-swizzled global source,
//           XOR-swizzled ds_read).
// Row stride of A and B must equal K.  C row stride = N.
// 256 threads = 4 waves (2x2), each wave owns a 64x64 output subtile.
// ---------------------------------------------------------------------------
template <int MODE>
__global__ __launch_bounds__(256) void gemm3p(
    const void* Ap, const void* ApLo,
    const void* Bp, const void* BpLo,
    float* __restrict__ C,
    int M, int N, int K,
    long long sAg, long long sBg, long long sCg,
    const float* bias, long long sBiasG,
    float alpha)
{
  constexpr int LD = (MODE == 1) ? 64 : 72;   // LDS pitch in bf16 elements
  __shared__ __align__(16) __bf16 sAhi[128 * LD];
  __shared__ __align__(16) __bf16 sAlo[128 * LD];
  __shared__ __align__(16) __bf16 sBhi[128 * LD];
  __shared__ __align__(16) __bf16 sBlo[128 * LD];

  const int t = threadIdx.x;
  const int g = blockIdx.z;
  const int m0 = blockIdx.y * 128, n0 = blockIdx.x * 128;
  const int lane = t & 63;
  const int w = t >> 6, wm = w >> 1, wn = w & 1;
  const int lr = lane & 15, lg = lane >> 4;

  const f32x4 fzero = {0.f, 0.f, 0.f, 0.f};
  f32x4 acc[4][4];
#pragma unroll
  for (int i = 0; i < 4; ++i)
#pragma unroll
    for (int j = 0; j < 4; ++j) acc[i][j] = fzero;

  for (int k0 = 0; k0 < K; k0 += 64) {
    __syncthreads();
    if constexpr (MODE == 1) {
      const __bf16* Ah = (const __bf16*)Ap + g * sAg;
      const __bf16* Al = (const __bf16*)ApLo + g * sAg;
      const __bf16* Bh = (const __bf16*)Bp + g * sBg;
      const __bf16* Bl = (const __bf16*)BpLo + g * sBg;
#pragma unroll
      for (int it = 0; it < 4; ++it) {
        int r = it * 32 + (t >> 3);            // tile row 0..127
        int sl = (t & 7) ^ (r & 7);            // swizzled 8-elem k-slot
        long long ea = (long long)(m0 + r) * K + k0 + sl * 8;
        long long eb = (long long)(n0 + r) * K + k0 + sl * 8;
        int dst = it * 4096 + (t >> 6) * 1024; // wave-uniform byte base
        gload_lds16(Ah + ea, (char*)sAhi + dst);
        gload_lds16(Al + ea, (char*)sAlo + dst);
        gload_lds16(Bh + eb, (char*)sBhi + dst);
        gload_lds16(Bl + eb, (char*)sBlo + dst);
      }
    } else {
      const float* A = (const float*)Ap + g * sAg;
      const float* B = (const float*)Bp + g * sBg;
      const int f = t & 15, r0 = t >> 4;
#pragma unroll
      for (int p = 0; p < 8; ++p) {
        int r = r0 + p * 16;
        float4 va = *(const float4*)(A + (long long)(m0 + r) * K + k0 + f * 4);
        float4 vb = *(const float4*)(B + (long long)(n0 + r) * K + k0 + f * 4);
        bf16x4 ah4, al4, bh4, bl4;
        __bf16 hh, ll;
        cvt_hilo(va.x, hh, ll); ah4[0] = hh; al4[0] = ll;
        cvt_hilo(va.y, hh, ll); ah4[1] = hh; al4[1] = ll;
        cvt_hilo(va.z, hh, ll); ah4[2] = hh; al4[2] = ll;
        cvt_hilo(va.w, hh, ll); ah4[3] = hh; al4[3] = ll;
        cvt_hilo(vb.x, hh, ll); bh4[0] = hh; bl4[0] = ll;
        cvt_hilo(vb.y, hh, ll); bh4[1] = hh; bl4[1] = ll;
        cvt_hilo(vb.z, hh, ll); bh4[2] = hh; bl4[2] = ll;
        cvt_hilo(vb.w, hh, ll); bh4[3] = hh; bl4[3] = ll;
        *(bf16x4*)&sAhi[r * LD + f * 4] = ah4;
        *(bf16x4*)&sAlo[r * LD + f * 4] = al4;
        *(bf16x4*)&sBhi[r * LD + f * 4] = bh4;
        *(bf16x4*)&sBlo[r * LD + f * 4] = bl4;
      }
    }
    __syncthreads();
#pragma unroll
    for (int ks = 0; ks < 2; ++ks) {
      bf16x8 ah[4], al[4], bh[4], bl[4];
#pragma unroll
      for (int i = 0; i < 4; ++i) {
        int ra = wm * 64 + i * 16 + lr;
        int rb = wn * 64 + i * 16 + lr;
        int oa, ob;
        if constexpr (MODE == 1) {
          oa = ra * 64 + (((ks * 4 + lg) ^ (ra & 7)) * 8);
          ob = rb * 64 + (((ks * 4 + lg) ^ (rb & 7)) * 8);
        } else {
          oa = ra * LD + ks * 32 + lg * 8;
          ob = rb * LD + ks * 32 + lg * 8;
        }
        ah[i] = *(const bf16x8*)&sAhi[oa];
        al[i] = *(const bf16x8*)&sAlo[oa];
        bh[i] = *(const bf16x8*)&sBhi[ob];
        bl[i] = *(const bf16x8*)&sBlo[ob];
      }
#pragma unroll
      for (int i = 0; i < 4; ++i)
#pragma unroll
        for (int j = 0; j < 4; ++j) {
          acc[i][j] = __builtin_amdgcn_mfma_f32_16x16x32_bf16(ah[i], bh[j], acc[i][j], 0, 0, 0);
          acc[i][j] = __builtin_amdgcn_mfma_f32_16x16x32_bf16(ah[i], bl[j], acc[i][j], 0, 0, 0);
          acc[i][j] = __builtin_amdgcn_mfma_f32_16x16x32_bf16(al[i], bh[j], acc[i][j], 0, 0, 0);
        }
    }
  }

  float* Cg = C + g * sCg;
  const float* bg = bias ? bias + g * sBiasG : nullptr;
#pragma unroll
  for (int i = 0; i < 4; ++i) {
    int row = m0 + wm * 64 + i * 16 + lg * 4;
#pragma unroll
    for (int j = 0; j < 4; ++j) {
      int col = n0 + wn * 64 + j * 16 + lr;
      float bb = bg ? bg[col] : 0.0f;
#pragma unroll
      for (int q = 0; q < 4; ++q)
        Cg[(long long)(row + q) * N + col] = acc[i][j][q] * alpha + bb;
    }
  }
}

// ---------------------------------------------------------------------------
// x [g][4096][512] fp32  ->  xT_hi/xT_lo [g][512][4096] bf16
// ---------------------------------------------------------------------------
__global__ __launch_bounds__(256) void transcvt_k(
    const float* __restrict__ x, __bf16* __restrict__ xTh, __bf16* __restrict__ xTl)
{
  __shared__ float tile[64][65];
  const int g = blockIdx.z, h0 = blockIdx.x * 64, s0 = blockIdx.y * 64;
  const int t = threadIdx.x, f = t & 15, r0 = t >> 4;
#pragma unroll
  for (int p = 0; p < 4; ++p) {
    int r = r0 + p * 16;
    float4 v = *(const float4*)(x + ((long long)g * 4096 + s0 + r) * 512 + h0 + f * 4);
    tile[f * 4 + 0][r] = v.x;
    tile[f * 4 + 1][r] = v.y;
    tile[f * 4 + 2][r] = v.z;
    tile[f * 4 + 3][r] = v.w;
  }
  __syncthreads();
  const int hr = t >> 2, sc = t & 3;
  long long ob = ((long long)g * 512 + h0 + hr) * 4096 + s0 + sc * 16;
#pragma unroll
  for (int i4 = 0; i4 < 4; ++i4) {
    bf16x4 hv, lv;
#pragma unroll
    for (int q = 0; q < 4; ++q) {
      __bf16 hh, ll;
      cvt_hilo(tile[hr][sc * 16 + i4 * 4 + q], hh, ll);
      hv[q] = hh; lv[q] = ll;
    }
    *(bf16x4*)(xTh + ob + i4 * 4) = hv;
    *(bf16x4*)(xTl + ob + i4 * 4) = lv;
  }
}

// ---------------------------------------------------------------------------
// fp32 transpose: src [g][M][N] -> dst [g][N][M]
// ---------------------------------------------------------------------------
__global__ __launch_bounds__(256) void transp_k(
    const float* __restrict__ src, float* __restrict__ dst,
    int M, int N, long long sg, long long sgT)
{
  __shared__ float tile[64][65];
  const int g = blockIdx.z, n0 = blockIdx.x * 64, m0 = blockIdx.y * 64;
  const int t = threadIdx.x, f = t & 15, r0 = t >> 4;
  const float* s = src + g * sg;
  float* d = dst + g * sgT;
#pragma unroll
  for (int p = 0; p < 4; ++p) {
    int r = r0 + p * 16;
    float4 v = *(const float4*)(s + (long long)(m0 + r) * N + n0 + f * 4);
    tile[f * 4 + 0][r] = v.x;
    tile[f * 4 + 1][r] = v.y;
    tile[f * 4 + 2][r] = v.z;
    tile[f * 4 + 3][r] = v.w;
  }
  __syncthreads();
  const int nr = t >> 2, mc = t & 3;
#pragma unroll
  for (int i4 = 0; i4 < 4; ++i4) {
    float4 o;
    o.x = tile[nr][mc * 16 + i4 * 4 + 0];
    o.y = tile[nr][mc * 16 + i4 * 4 + 1];
    o.z = tile[nr][mc * 16 + i4 * 4 + 2];
    o.w = tile[nr][mc * 16 + i4 * 4 + 3];
    *(float4*)(d + (long long)(n0 + nr) * M + m0 + mc * 16 + i4 * 4) = o;
  }
}

// ---------------------------------------------------------------------------
// ssum[g][h] = sum_s x[g][s][h]   (atomic partials; ssum pre-zeroed)
// ---------------------------------------------------------------------------
__global__ __launch_bounds__(256) void colsum_k(const float* __restrict__ x, float* __restrict__ ssum)
{
  const int g = blockIdx.z, h = blockIdx.x * 256 + threadIdx.x, sb = blockIdx.y;
  float p = 0.f;
  for (int s = sb * 64; s < sb * 64 + 64; ++s)
    p += x[((long long)g * 4096 + s) * 512 + h];
  atomicAdd(&ssum[g * 512 + h], p);
}

// rho[g][d] = (ssum_g @ Wq)(d) ; kap[g][e] = (ssum_g @ Wk)(e)
__global__ __launch_bounds__(256) void rk_k(
    const float* __restrict__ ssum, const float* __restrict__ Wq, const float* __restrict__ Wk,
    float* __restrict__ rho, float* __restrict__ kap)
{
  const int g = blockIdx.y, d = blockIdx.x * 256 + threadIdx.x;
  float r = 0.f, k = 0.f;
  for (int f = 0; f < 512; ++f) {
    float s = ssum[g * 512 + f];
    r += s * Wq[f * 512 + d];
    k += s * Wk[f * 512 + d];
  }
  rho[g * 512 + d] = r;
  kap[g * 512 + d] = k;
}

// ---------------------------------------------------------------------------
// Row softmax over SC [g][d][e] in-place, adding bias rank-1 terms:
//   z = SC + alpha*(bq[d]*kap[e] + bk[e]*(rho[d] + 4096*bq[d]))
// One wave per row.
// ---------------------------------------------------------------------------
__global__ __launch_bounds__(256) void softmax_k(
    float* __restrict__ SC, const float* __restrict__ rho, const float* __restrict__ kap,
    const float* __restrict__ bq, const float* __restrict__ bk, float alpha)
{
  const int rowid = blockIdx.x * 4 + (threadIdx.x >> 6);
  const int g = rowid >> 9, d = rowid & 511;
  const int l = threadIdx.x & 63;
  float* row = SC + (long long)rowid * 512;
  const float bqd = bq[d];
  const float rr = rho[g * 512 + d] + 4096.f * bqd;
  float4 z0 = *(float4*)(row + l * 8);
  float4 z1 = *(float4*)(row + l * 8 + 4);
  float4 bk0 = *(const float4*)(bk + l * 8);
  float4 bk1 = *(const float4*)(bk + l * 8 + 4);
  float4 kp0 = *(const float4*)(kap + g * 512 + l * 8);
  float4 kp1 = *(const float4*)(kap + g * 512 + l * 8 + 4);
  float z[8];
  z[0] = z0.x + alpha * (bqd * kp0.x + bk0.x * rr);
  z[1] = z0.y + alpha * (bqd * kp0.y + bk0.y * rr);
  z[2] = z0.z + alpha * (bqd * kp0.z + bk0.z * rr);
  z[3] = z0.w + alpha * (bqd * kp0.w + bk0.w * rr);
  z[4] = z1.x + alpha * (bqd * kp1.x + bk1.x * rr);
  z[5] = z1.y + alpha * (bqd * kp1.y + bk1.y * rr);
  z[6] = z1.z + alpha * (bqd * kp1.z + bk1.z * rr);
  z[7] = z1.w + alpha * (bqd * kp1.w + bk1.w * rr);
  float m = z[0];
#pragma unroll
  for (int j = 1; j < 8; ++j) m = fmaxf(m, z[j]);
  for (int o = 32; o; o >>= 1) m = fmaxf(m, __shfl_xor(m, o));
  float sum = 0.f;
#pragma unroll
  for (int j = 0; j < 8; ++j) { z[j] = __expf(z[j] - m); sum += z[j]; }
  for (int o = 32; o; o >>= 1) sum += __shfl_xor(sum, o);
  const float inv = 1.0f / sum;
  *(float4*)(row + l * 8)     = make_float4(z[0] * inv, z[1] * inv, z[2] * inv, z[3] * inv);
  *(float4*)(row + l * 8 + 4) = make_float4(z[4] * inv, z[5] * inv, z[6] * inv, z[7] * inv);
}

// c[g][h] = sum_e bv[e]*Aat[g][e][h] + bo[h]   (atomic partials; c pre-zeroed)
__global__ __launch_bounds__(256) void cvec_k(
    const float* __restrict__ Aat, const float* __restrict__ bv, const float* __restrict__ bo,
    float* __restrict__ c)
{
  const int g = blockIdx.z, h = blockIdx.x * 256 + threadIdx.x, eb = blockIdx.y;
  float p = (eb == 0) ? bo[h] : 0.f;
  for (int e = eb * 64; e < eb * 64 + 64; ++e)
    p += bv[e] * Aat[((long long)g * 512 + e) * 512 + h];
  atomicAdd(&c[g * 512 + h], p);
}

// ---------------------------------------------------------------------------
extern "C" void kernel_launch(void* const* d_in, const int* in_sizes, int n_in,
                              void* d_out, int out_size, void* d_ws, size_t ws_size,
                              hipStream_t stream) {
  (void)in_sizes; (void)n_in; (void)out_size; (void)ws_size;
  const float* x  = (const float*)d_in[0];
  const float* Wq = (const float*)d_in[1];
  const float* bq = (const float*)d_in[2];
  const float* Wk = (const float*)d_in[3];
  const float* bk = (const float*)d_in[4];
  const float* Wv = (const float*)d_in[5];
  const float* bv = (const float*)d_in[6];
  const float* Wo = (const float*)d_in[7];
  const float* bo = (const float*)d_in[8];
  float* out = (float*)d_out;

  char* ws = (char*)d_ws;
  __bf16* xTh = (__bf16*)(ws);                       // 64 MiB
  __bf16* xTl = (__bf16*)(ws + 67108864);            // 64 MiB
  float* S1   = (float*)(ws + 134217728);            // 16 MiB: G -> attnT -> PT
  float* S2   = (float*)(ws + 150994944);            // 16 MiB: T1T -> Aat
  float* S3   = (float*)(ws + 167772160);            // 16 MiB: SC/attn -> AatT
  float* WqT  = (float*)(ws + 184549376);            // 1 MiB
  float* WkT  = (float*)(ws + 185597952);            // 1 MiB
  float* WoT  = (float*)(ws + 186646528);            // 1 MiB
  float* ssum = (float*)(ws + 187695104);            // 32 KiB
  float* cbuf = (float*)(ws + 187695104 + 32768);    // 32 KiB
  float* rho  = (float*)(ws + 187695104 + 65536);    // 32 KiB
  float* kap  = (float*)(ws + 187695104 + 98304);    // 32 KiB

  const long long SXT = 512LL * 4096;   // per-g stride of xT
  const long long SM  = 512LL * 512;    // per-g stride of 512x512 mats
  const long long SX  = 4096LL * 512;   // per-g stride of x / out
  const float alpha = 0.04419417382415922f;  // 1/sqrt(512)

  hipMemsetAsync(ssum, 0, 65536, stream);  // zeros ssum + cbuf

  colsum_k<<<dim3(2, 64, 16), 256, 0, stream>>>(x, ssum);
  transcvt_k<<<dim3(8, 64, 16), 256, 0, stream>>>(x, xTh, xTl);
  rk_k<<<dim3(2, 16), 256, 0, stream>>>(ssum, Wq, Wk, rho, kap);
  transp_k<<<dim3(8, 8, 1), 256, 0, stream>>>(Wq, WqT, 512, 512, 0, 0);
  transp_k<<<dim3(8, 8, 1), 256, 0, stream>>>(Wk, WkT, 512, 512, 0, 0);
  transp_k<<<dim3(8, 8, 1), 256, 0, stream>>>(Wo, WoT, 512, 512, 0, 0);

  // G = x^T x  (exact to O(2^-16)): S1[g][d][e]
  gemm3p<1><<<dim3(4, 4, 16), 256, 0, stream>>>(
      xTh, xTl, xTh, xTl, S1, 512, 512, 4096, SXT, SXT, SM, nullptr, 0, 1.0f);
  // T1T[e][a] = sum_f Wk(f,e) G(a,f)
  gemm3p<0><<<dim3(4, 4, 16), 256, 0, stream>>>(
      WkT, nullptr, S1, nullptr, S2, 512, 512, 512, 0, SM, SM, nullptr, 0, 1.0f);
  // SC[d][e] = alpha * sum_a Wq(a,d) T1T(e,a)
  gemm3p<0><<<dim3(4, 4, 16), 256, 0, stream>>>(
      WqT, nullptr, S2, nullptr, S3, 512, 512, 512, 0, SM, SM, nullptr, 0, alpha);
  softmax_k<<<2048, 256, 0, stream>>>(S3, rho, kap, bq, bk, alpha);
  // attnT[e][d] <- attn[d][e]
  transp_k<<<dim3(8, 8, 16), 256, 0, stream>>>(S3, S1, 512, 512, SM, SM);
  // Aat[e][h] = sum_d attn(d,e) Wo(d,h)
  gemm3p<0><<<dim3(4, 4, 16), 256, 0, stream>>>(
      S1, nullptr, WoT, nullptr, S2, 512, 512, 512, SM, 0, SM, nullptr, 0, 1.0f);
  cvec_k<<<dim3(2, 8, 16), 256, 0, stream>>>(S2, bv, bo, cbuf);
  // AatT[h][e] <- Aat[e][h]
  transp_k<<<dim3(8, 8, 16), 256, 0, stream>>>(S2, S3, 512, 512, SM, SM);
  // PT[h][f] = sum_e AatT(h,e) Wv(f,e)
  gemm3p<0><<<dim3(4, 4, 16), 256, 0, stream>>>(
      S3, nullptr, Wv, nullptr, S1, 512, 512, 512, SM, 0, SM, nullptr, 0, 1.0f);
  // out[g][s][h] = sum_f x(s,f) PT(h,f) + c[g][h]
  gemm3p<0><<<dim3(4, 32, 16), 256, 0, stream>>>(
      x, nullptr, S1, nullptr, out, 4096, 512, 512, SX, SM, SX, cbuf, 512, 1.0f);
}

// Round 2
// 717.290 us; speedup vs baseline: 1.1931x; 1.1931x over previous
//
#include <hip/hip_runtime.h>
#include <hip/hip_bf16.h>

// ---------------------------------------------------------------------------
// MultiHeadSelfAttention (nh=1) via the feature Gram matrix.
//   G_g   = x_g^T x_g  (symmetric -> lower-triangle blocks + mirror)
//   SC_g  = (Wq^T G_g Wk)/sqrt(512) + bias rank-1 terms
//   attn  = softmax_rows(SC)
//   Aat_g = attn^T Wo ;  P_g = Wv Aat_g ;  c_g = bv Aat_g + bo
//   out_g = x_g P_g + c_g
// GEMMs: bf16 hi/lo split, 3 MFMA passes (fp32-class accuracy).
// ---------------------------------------------------------------------------

typedef __attribute__((ext_vector_type(4))) float f32x4;
typedef __attribute__((ext_vector_type(8))) __bf16 bf16x8;
typedef __attribute__((ext_vector_type(4))) __bf16 bf16x4;

typedef __attribute__((address_space(1))) const void gconst_void;
typedef __attribute__((address_space(3))) void lds_void;

__device__ __forceinline__ void gload_lds16(const void* g, void* l) {
  __builtin_amdgcn_global_load_lds((gconst_void*)g, (lds_void*)l, 16, 0, 0);
}

__device__ __forceinline__ void cvt_hilo(float v, __bf16& h, __bf16& l) {
  h = (__bf16)v;
  l = (__bf16)(v - (float)h);
}

// ---------------------------------------------------------------------------
// Tile GEMM:  C[m][n] = alpha * sum_k Ain(m,k)*Bin(n,k)  (+bias[n])
//   MODE 0: A,B fp32 row-major [.][K]; cvt to bf16 hi/lo during staging.
//   MODE 1: A,B bf16 hi/lo pairs row-major [.][K]; global_load_lds staging
//           (linear LDS dest, XOR-swizzled global source + ds_read).
//   BMN:  tile edge (64 or 128).  BK = 64.  4 waves, 2x2 wave grid.
//   tri:  blockIdx.x is a linear lower-triangle 128-block pair index,
//         blockIdx.y is the split-K chunk.
//   splitK>1: epilogue is atomicAdd (C must be pre-zeroed), bias ignored.
// ---------------------------------------------------------------------------
template <int MODE, int BMN>
__global__ __launch_bounds__(256) void gemm3p(
    const void* Ap, const void* ApLo,
    const void* Bp, const void* BpLo,
    float* __restrict__ C,
    int M, int N, int K,
    long long sAg, long long sBg, long long sCg,
    const float* bias, long long sBiasG,
    float alpha, int tri, int splitK)
{
  constexpr int LD = (MODE == 1) ? 64 : 72;   // LDS pitch in bf16 elements
  constexpr int R = BMN / 32;                 // 16x16 frags per wave dim
  __shared__ __align__(16) __bf16 sAhi[BMN * LD];
  __shared__ __align__(16) __bf16 sAlo[BMN * LD];
  __shared__ __align__(16) __bf16 sBhi[BMN * LD];
  __shared__ __align__(16) __bf16 sBlo[BMN * LD];

  const int t = threadIdx.x;
  const int g = blockIdx.z;
  int m0, n0, kBeg, kEnd;
  if (tri) {
    int p = blockIdx.x, bx = 0;
    while ((bx + 1) * (bx + 2) / 2 <= p) ++bx;
    int by = p - bx * (bx + 1) / 2;
    m0 = bx * BMN; n0 = by * BMN;
    int kLen = K / splitK;
    kBeg = blockIdx.y * kLen; kEnd = kBeg + kLen;
  } else {
    m0 = blockIdx.y * BMN; n0 = blockIdx.x * BMN;
    kBeg = 0; kEnd = K;
  }
  const int lane = t & 63;
  const int w = t >> 6, wm = w >> 1, wn = w & 1;
  const int lr = lane & 15, lg = lane >> 4;

  const f32x4 fzero = {0.f, 0.f, 0.f, 0.f};
  f32x4 acc[R][R];
#pragma unroll
  for (int i = 0; i < R; ++i)
#pragma unroll
    for (int j = 0; j < R; ++j) acc[i][j] = fzero;

  for (int k0 = kBeg; k0 < kEnd; k0 += 64) {
    __syncthreads();
    if constexpr (MODE == 1) {
      const __bf16* Ah = (const __bf16*)Ap + g * sAg;
      const __bf16* Al = (const __bf16*)ApLo + g * sAg;
      const __bf16* Bh = (const __bf16*)Bp + g * sBg;
      const __bf16* Bl = (const __bf16*)BpLo + g * sBg;
#pragma unroll
      for (int it = 0; it < BMN / 32; ++it) {
        int r = it * 32 + (t >> 3);            // tile row
        int sl = (t & 7) ^ (r & 7);            // swizzled 8-elem k-slot
        long long ea = (long long)(m0 + r) * K + k0 + sl * 8;
        long long eb = (long long)(n0 + r) * K + k0 + sl * 8;
        int dst = it * 4096 + (t >> 6) * 1024; // wave-uniform byte base
        gload_lds16(Ah + ea, (char*)sAhi + dst);
        gload_lds16(Al + ea, (char*)sAlo + dst);
        gload_lds16(Bh + eb, (char*)sBhi + dst);
        gload_lds16(Bl + eb, (char*)sBlo + dst);
      }
    } else {
      const float* A = (const float*)Ap + g * sAg;
      const float* B = (const float*)Bp + g * sBg;
      const int f = t & 15, r0 = t >> 4;
#pragma unroll
      for (int p = 0; p < BMN / 16; ++p) {
        int r = r0 + p * 16;
        float4 va = *(const float4*)(A + (long long)(m0 + r) * K + k0 + f * 4);
        float4 vb = *(const float4*)(B + (long long)(n0 + r) * K + k0 + f * 4);
        bf16x4 ah4, al4, bh4, bl4;
        __bf16 hh, ll;
        cvt_hilo(va.x, hh, ll); ah4[0] = hh; al4[0] = ll;
        cvt_hilo(va.y, hh, ll); ah4[1] = hh; al4[1] = ll;
        cvt_hilo(va.z, hh, ll); ah4[2] = hh; al4[2] = ll;
        cvt_hilo(va.w, hh, ll); ah4[3] = hh; al4[3] = ll;
        cvt_hilo(vb.x, hh, ll); bh4[0] = hh; bl4[0] = ll;
        cvt_hilo(vb.y, hh, ll); bh4[1] = hh; bl4[1] = ll;
        cvt_hilo(vb.z, hh, ll); bh4[2] = hh; bl4[2] = ll;
        cvt_hilo(vb.w, hh, ll); bh4[3] = hh; bl4[3] = ll;
        *(bf16x4*)&sAhi[r * LD + f * 4] = ah4;
        *(bf16x4*)&sAlo[r * LD + f * 4] = al4;
        *(bf16x4*)&sBhi[r * LD + f * 4] = bh4;
        *(bf16x4*)&sBlo[r * LD + f * 4] = bl4;
      }
    }
    __syncthreads();
#pragma unroll
    for (int ks = 0; ks < 2; ++ks) {
      bf16x8 ah[R], al[R], bh[R], bl[R];
#pragma unroll
      for (int i = 0; i < R; ++i) {
        int ra = wm * (BMN / 2) + i * 16 + lr;
        int rb = wn * (BMN / 2) + i * 16 + lr;
        int oa, ob;
        if constexpr (MODE == 1) {
          oa = ra * 64 + (((ks * 4 + lg) ^ (ra & 7)) * 8);
          ob = rb * 64 + (((ks * 4 + lg) ^ (rb & 7)) * 8);
        } else {
          oa = ra * LD + ks * 32 + lg * 8;
          ob = rb * LD + ks * 32 + lg * 8;
        }
        ah[i] = *(const bf16x8*)&sAhi[oa];
        al[i] = *(const bf16x8*)&sAlo[oa];
        bh[i] = *(const bf16x8*)&sBhi[ob];
        bl[i] = *(const bf16x8*)&sBlo[ob];
      }
#pragma unroll
      for (int i = 0; i < R; ++i)
#pragma unroll
        for (int j = 0; j < R; ++j) {
          acc[i][j] = __builtin_amdgcn_mfma_f32_16x16x32_bf16(ah[i], bh[j], acc[i][j], 0, 0, 0);
          acc[i][j] = __builtin_amdgcn_mfma_f32_16x16x32_bf16(ah[i], bl[j], acc[i][j], 0, 0, 0);
          acc[i][j] = __builtin_amdgcn_mfma_f32_16x16x32_bf16(al[i], bh[j], acc[i][j], 0, 0, 0);
        }
    }
  }

  float* Cg = C + g * sCg;
  const float* bg = bias ? bias + g * sBiasG : nullptr;
#pragma unroll
  for (int i = 0; i < R; ++i) {
    int row = m0 + wm * (BMN / 2) + i * 16 + lg * 4;
#pragma unroll
    for (int j = 0; j < R; ++j) {
      int col = n0 + wn * (BMN / 2) + j * 16 + lr;
      if (splitK > 1) {
#pragma unroll
        for (int q = 0; q < 4; ++q)
          atomicAdd(&Cg[(long long)(row + q) * N + col], acc[i][j][q] * alpha);
      } else {
        float bb = bg ? bg[col] : 0.0f;
#pragma unroll
        for (int q = 0; q < 4; ++q)
          Cg[(long long)(row + q) * N + col] = acc[i][j][q] * alpha + bb;
      }
    }
  }
}

// ---------------------------------------------------------------------------
// x [g][4096][512] fp32 -> xT_hi/xT_lo [g][512][4096] bf16, fused col-sums
// ---------------------------------------------------------------------------
__global__ __launch_bounds__(256) void transcvt_k(
    const float* __restrict__ x, __bf16* __restrict__ xTh, __bf16* __restrict__ xTl,
    float* __restrict__ ssum)
{
  __shared__ float tile[64][65];
  const int g = blockIdx.z, h0 = blockIdx.x * 64, s0 = blockIdx.y * 64;
  const int t = threadIdx.x, f = t & 15, r0 = t >> 4;
#pragma unroll
  for (int p = 0; p < 4; ++p) {
    int r = r0 + p * 16;
    float4 v = *(const float4*)(x + ((long long)g * 4096 + s0 + r) * 512 + h0 + f * 4);
    tile[f * 4 + 0][r] = v.x;
    tile[f * 4 + 1][r] = v.y;
    tile[f * 4 + 2][r] = v.z;
    tile[f * 4 + 3][r] = v.w;
  }
  __syncthreads();
  const int hr = t >> 2, sc = t & 3;
  long long ob = ((long long)g * 512 + h0 + hr) * 4096 + s0 + sc * 16;
  float csum = 0.f;
#pragma unroll
  for (int i4 = 0; i4 < 4; ++i4) {
    bf16x4 hv, lv;
#pragma unroll
    for (int q = 0; q < 4; ++q) {
      float vv = tile[hr][sc * 16 + i4 * 4 + q];
      csum += vv;
      __bf16 hh, ll;
      cvt_hilo(vv, hh, ll);
      hv[q] = hh; lv[q] = ll;
    }
    *(bf16x4*)(xTh + ob + i4 * 4) = hv;
    *(bf16x4*)(xTl + ob + i4 * 4) = lv;
  }
  csum += __shfl_xor(csum, 1);
  csum += __shfl_xor(csum, 2);
  if ((t & 3) == 0) atomicAdd(&ssum[g * 512 + h0 + hr], csum);
}

// ---------------------------------------------------------------------------
// fp32 transpose: src [g][M][N] -> dst [g][N][M].
// triOnly=1: only tiles with m0>n0 (in-place symmetric mirror: dst==src).
// ---------------------------------------------------------------------------
__global__ __launch_bounds__(256) void transp_k(
    const float* __restrict__ src, float* __restrict__ dst,
    int M, int N, long long sg, long long sgT, int triOnly)
{
  __shared__ float tile[64][65];
  const int g = blockIdx.z, n0 = blockIdx.x * 64, m0 = blockIdx.y * 64;
  if (triOnly && m0 <= n0) return;
  const int t = threadIdx.x, f = t & 15, r0 = t >> 4;
  const float* s = src + g * sg;
  float* d = dst + g * sgT;
#pragma unroll
  for (int p = 0; p < 4; ++p) {
    int r = r0 + p * 16;
    float4 v = *(const float4*)(s + (long long)(m0 + r) * N + n0 + f * 4);
    tile[f * 4 + 0][r] = v.x;
    tile[f * 4 + 1][r] = v.y;
    tile[f * 4 + 2][r] = v.z;
    tile[f * 4 + 3][r] = v.w;
  }
  __syncthreads();
  const int nr = t >> 2, mc = t & 3;
#pragma unroll
  for (int i4 = 0; i4 < 4; ++i4) {
    float4 o;
    o.x = tile[nr][mc * 16 + i4 * 4 + 0];
    o.y = tile[nr][mc * 16 + i4 * 4 + 1];
    o.z = tile[nr][mc * 16 + i4 * 4 + 2];
    o.w = tile[nr][mc * 16 + i4 * 4 + 3];
    *(float4*)(d + (long long)(n0 + nr) * M + m0 + mc * 16 + i4 * 4) = o;
  }
}

// Merged weight transposes: z selects Wq/Wk/Wo (512x512 each).
__global__ __launch_bounds__(256) void wtrans_k(
    const float* __restrict__ Wq, const float* __restrict__ Wk, const float* __restrict__ Wo,
    float* __restrict__ WqT, float* __restrict__ WkT, float* __restrict__ WoT)
{
  __shared__ float tile[64][65];
  const int z = blockIdx.z;
  const float* s = (z == 0) ? Wq : (z == 1) ? Wk : Wo;
  float* d = (z == 0) ? WqT : (z == 1) ? WkT : WoT;
  const int n0 = blockIdx.x * 64, m0 = blockIdx.y * 64;
  const int t = threadIdx.x, f = t & 15, r0 = t >> 4;
#pragma unroll
  for (int p = 0; p < 4; ++p) {
    int r = r0 + p * 16;
    float4 v = *(const float4*)(s + (long long)(m0 + r) * 512 + n0 + f * 4);
    tile[f * 4 + 0][r] = v.x;
    tile[f * 4 + 1][r] = v.y;
    tile[f * 4 + 2][r] = v.z;
    tile[f * 4 + 3][r] = v.w;
  }
  __syncthreads();
  const int nr = t >> 2, mc = t & 3;
#pragma unroll
  for (int i4 = 0; i4 < 4; ++i4) {
    float4 o;
    o.x = tile[nr][mc * 16 + i4 * 4 + 0];
    o.y = tile[nr][mc * 16 + i4 * 4 + 1];
    o.z = tile[nr][mc * 16 + i4 * 4 + 2];
    o.w = tile[nr][mc * 16 + i4 * 4 + 3];
    *(float4*)(d + (long long)(n0 + nr) * 512 + m0 + mc * 16 + i4 * 4) = o;
  }
}

// fp32 -> bf16 hi/lo, grid-stride over float4s.
__global__ __launch_bounds__(256) void cvt32_k(
    const float* __restrict__ src, __bf16* __restrict__ h, __bf16* __restrict__ l,
    long long n4)
{
  long long stride = (long long)gridDim.x * 256;
  for (long long i = blockIdx.x * 256LL + threadIdx.x; i < n4; i += stride) {
    float4 v = ((const float4*)src)[i];
    bf16x4 hv, lv;
    __bf16 hh, ll;
    cvt_hilo(v.x, hh, ll); hv[0] = hh; lv[0] = ll;
    cvt_hilo(v.y, hh, ll); hv[1] = hh; lv[1] = ll;
    cvt_hilo(v.z, hh, ll); hv[2] = hh; lv[2] = ll;
    cvt_hilo(v.w, hh, ll); hv[3] = hh; lv[3] = ll;
    *(bf16x4*)(h + i * 4) = hv;
    *(bf16x4*)(l + i * 4) = lv;
  }
}

// rho[g][d] = (ssum_g @ Wq)(d) ; kap[g][e] = (ssum_g @ Wk)(e)
__global__ __launch_bounds__(256) void rk_k(
    const float* __restrict__ ssum, const float* __restrict__ Wq, const float* __restrict__ Wk,
    float* __restrict__ rho, float* __restrict__ kap)
{
  const int g = blockIdx.y, d = blockIdx.x * 256 + threadIdx.x;
  float r = 0.f, k = 0.f;
  for (int f = 0; f < 512; ++f) {
    float s = ssum[g * 512 + f];
    r += s * Wq[f * 512 + d];
    k += s * Wk[f * 512 + d];
  }
  rho[g * 512 + d] = r;
  kap[g * 512 + d] = k;
}

// Row softmax over SC [g][d][e] in-place with bias rank-1 terms.
__global__ __launch_bounds__(256) void softmax_k(
    float* __restrict__ SC, const float* __restrict__ rho, const float* __restrict__ kap,
    const float* __restrict__ bq, const float* __restrict__ bk, float alpha)
{
  const int rowid = blockIdx.x * 4 + (threadIdx.x >> 6);
  const int g = rowid >> 9, d = rowid & 511;
  const int l = threadIdx.x & 63;
  float* row = SC + (long long)rowid * 512;
  const float bqd = bq[d];
  const float rr = rho[g * 512 + d] + 4096.f * bqd;
  float4 z0 = *(float4*)(row + l * 8);
  float4 z1 = *(float4*)(row + l * 8 + 4);
  float4 bk0 = *(const float4*)(bk + l * 8);
  float4 bk1 = *(const float4*)(bk + l * 8 + 4);
  float4 kp0 = *(const float4*)(kap + g * 512 + l * 8);
  float4 kp1 = *(const float4*)(kap + g * 512 + l * 8 + 4);
  float z[8];
  z[0] = z0.x + alpha * (bqd * kp0.x + bk0.x * rr);
  z[1] = z0.y + alpha * (bqd * kp0.y + bk0.y * rr);
  z[2] = z0.z + alpha * (bqd * kp0.z + bk0.z * rr);
  z[3] = z0.w + alpha * (bqd * kp0.w + bk0.w * rr);
  z[4] = z1.x + alpha * (bqd * kp1.x + bk1.x * rr);
  z[5] = z1.y + alpha * (bqd * kp1.y + bk1.y * rr);
  z[6] = z1.z + alpha * (bqd * kp1.z + bk1.z * rr);
  z[7] = z1.w + alpha * (bqd * kp1.w + bk1.w * rr);
  float m = z[0];
#pragma unroll
  for (int j = 1; j < 8; ++j) m = fmaxf(m, z[j]);
  for (int o = 32; o; o >>= 1) m = fmaxf(m, __shfl_xor(m, o));
  float sum = 0.f;
#pragma unroll
  for (int j = 0; j < 8; ++j) { z[j] = __expf(z[j] - m); sum += z[j]; }
  for (int o = 32; o; o >>= 1) sum += __shfl_xor(sum, o);
  const float inv = 1.0f / sum;
  *(float4*)(row + l * 8)     = make_float4(z[0] * inv, z[1] * inv, z[2] * inv, z[3] * inv);
  *(float4*)(row + l * 8 + 4) = make_float4(z[4] * inv, z[5] * inv, z[6] * inv, z[7] * inv);
}

// c[g][h] = sum_e bv[e]*Aat[g][e][h] + bo[h]
__global__ __launch_bounds__(256) void cvec_k(
    const float* __restrict__ Aat, const float* __restrict__ bv, const float* __restrict__ bo,
    float* __restrict__ c)
{
  const int g = blockIdx.z, h = blockIdx.x * 256 + threadIdx.x, eb = blockIdx.y;
  float p = (eb == 0) ? bo[h] : 0.f;
  for (int e = eb * 64; e < eb * 64 + 64; ++e)
    p += bv[e] * Aat[((long long)g * 512 + e) * 512 + h];
  atomicAdd(&c[g * 512 + h], p);
}

// ---------------------------------------------------------------------------
extern "C" void kernel_launch(void* const* d_in, const int* in_sizes, int n_in,
                              void* d_out, int out_size, void* d_ws, size_t ws_size,
                              hipStream_t stream) {
  (void)in_sizes; (void)n_in; (void)out_size; (void)ws_size;
  const float* x  = (const float*)d_in[0];
  const float* Wq = (const float*)d_in[1];
  const float* bq = (const float*)d_in[2];
  const float* Wk = (const float*)d_in[3];
  const float* bk = (const float*)d_in[4];
  const float* Wv = (const float*)d_in[5];
  const float* bv = (const float*)d_in[6];
  const float* Wo = (const float*)d_in[7];
  const float* bo = (const float*)d_in[8];
  float* out = (float*)d_out;

  char* ws = (char*)d_ws;
  __bf16* xTh = (__bf16*)(ws);                       // 64 MiB (reused as xnh)
  __bf16* xTl = (__bf16*)(ws + 67108864);            // 64 MiB (reused as xnl)
  float* S1   = (float*)(ws + 134217728);            // 16 MiB: G -> attnT -> PT
  float* S2   = (float*)(ws + 150994944);            // 16 MiB: T1T -> Aat -> PThi/lo
  float* S3   = (float*)(ws + 167772160);            // 16 MiB: SC/attn -> AatT
  float* WqT  = (float*)(ws + 184549376);            // 1 MiB
  float* WkT  = (float*)(ws + 185597952);            // 1 MiB
  float* WoT  = (float*)(ws + 186646528);            // 1 MiB
  float* ssum = (float*)(ws + 187695104);            // 32 KiB
  float* cbuf = (float*)(ws + 187695104 + 32768);    // 32 KiB
  float* rho  = (float*)(ws + 187695104 + 65536);    // 32 KiB
  float* kap  = (float*)(ws + 187695104 + 98304);    // 32 KiB

  __bf16* PThi = (__bf16*)S2;                        // overlay (Aat dead)
  __bf16* PTlo = (__bf16*)((char*)S2 + 8388608);
  __bf16* xnh = xTh;                                 // overlay (xT dead post-Gram)
  __bf16* xnl = xTl;

  const long long SXT = 512LL * 4096;
  const long long SM  = 512LL * 512;
  const long long SX  = 4096LL * 512;
  const float alpha = 0.04419417382415922f;  // 1/sqrt(512)

  hipMemsetAsync(ssum, 0, 65536, stream);       // ssum + cbuf
  hipMemsetAsync(S1, 0, 16777216, stream);      // Gram atomic target

  transcvt_k<<<dim3(8, 64, 16), 256, 0, stream>>>(x, xTh, xTl, ssum);
  wtrans_k<<<dim3(8, 8, 3), 256, 0, stream>>>(Wq, Wk, Wo, WqT, WkT, WoT);
  rk_k<<<dim3(2, 16), 256, 0, stream>>>(ssum, Wq, Wk, rho, kap);

  // G = x^T x : lower-triangle 128-blocks, split-K=4, atomicAdd into S1
  gemm3p<1, 128><<<dim3(10, 4, 16), 256, 0, stream>>>(
      xTh, xTl, xTh, xTl, S1, 512, 512, 4096, SXT, SXT, SM, nullptr, 0, 1.0f, 1, 4);
  // mirror lower -> upper (in-place)
  transp_k<<<dim3(8, 8, 16), 256, 0, stream>>>(S1, S1, 512, 512, SM, SM, 1);

  // T1T[e][a] = sum_f Wk(f,e) G(a,f)
  gemm3p<0, 64><<<dim3(8, 8, 16), 256, 0, stream>>>(
      WkT, nullptr, S1, nullptr, S2, 512, 512, 512, 0, SM, SM, nullptr, 0, 1.0f, 0, 1);
  // SC[d][e] = alpha * sum_a Wq(a,d) T1T(e,a)
  gemm3p<0, 64><<<dim3(8, 8, 16), 256, 0, stream>>>(
      WqT, nullptr, S2, nullptr, S3, 512, 512, 512, 0, SM, SM, nullptr, 0, alpha, 0, 1);
  softmax_k<<<2048, 256, 0, stream>>>(S3, rho, kap, bq, bk, alpha);
  // attnT[e][d] <- attn[d][e]
  transp_k<<<dim3(8, 8, 16), 256, 0, stream>>>(S3, S1, 512, 512, SM, SM, 0);
  // Aat[e][h] = sum_d attnT(e,d) WoT(h,d)
  gemm3p<0, 64><<<dim3(8, 8, 16), 256, 0, stream>>>(
      S1, nullptr, WoT, nullptr, S2, 512, 512, 512, SM, 0, SM, nullptr, 0, 1.0f, 0, 1);
  cvec_k<<<dim3(2, 8, 16), 256, 0, stream>>>(S2, bv, bo, cbuf);
  // AatT[h][e] <- Aat[e][h]
  transp_k<<<dim3(8, 8, 16), 256, 0, stream>>>(S2, S3, 512, 512, SM, SM, 0);
  // PT[h][f] = sum_e AatT(h,e) Wv(f,e)
  gemm3p<0, 64><<<dim3(8, 8, 16), 256, 0, stream>>>(
      S3, nullptr, Wv, nullptr, S1, 512, 512, 512, SM, 0, SM, nullptr, 0, 1.0f, 0, 1);

  // convert PT and x to bf16 hi/lo for the MODE-1 final GEMM
  cvt32_k<<<2048, 256, 0, stream>>>(S1, PThi, PTlo, 16LL * 512 * 512 / 4);
  cvt32_k<<<2048, 256, 0, stream>>>(x, xnh, xnl, 16LL * 4096 * 512 / 4);

  // out[g][s][h] = sum_f x(s,f) PT(h,f) + c[g][h]
  gemm3p<1, 128><<<dim3(4, 32, 16), 256, 0, stream>>>(
      xnh, xnl, PThi, PTlo, out, 4096, 512, 512, SX, SM, SX, cbuf, 512, 1.0f, 0, 1);
}